// Round 6
// baseline (379.968 us; speedup 1.0000x reference)
//
#include <hip/hip_runtime.h>
#include <limits.h>
#include <stdint.h>

#define ALPHA 0.2f
#define HALFA 0.1f
static constexpr int N = 8192;
static constexpr int D = 128;
static constexpr int C = 512;
static constexpr int BI = 128;   // block tile rows (i)
static constexpr int BJ = 64;    // block tile cols (j)
static constexpr int KC = 64;    // k-chunk in fp16 elems
static constexpr int SL = 72;    // LDS row stride in fp16 (64 + 8 pad; 0 conflicts measured R5)
static constexpr int NBLK = (N / BI) * (N / BJ);   // 64 * 128 = 8192

using half8   = __attribute__((ext_vector_type(8))) _Float16;
using half2v  = __attribute__((ext_vector_type(2))) _Float16;
using floatx16 = __attribute__((ext_vector_type(16))) float;

__device__ __forceinline__ floatx16 zerov() { floatx16 v = {0.f}; return v; }

// ---------------- setup: 1 block computes all anchors + zeroes counter ----------------

__global__ void k_anchor(const int* __restrict__ labels, int* __restrict__ anchor,
                         unsigned int* __restrict__ counter) {
    __shared__ int sa[C];
    int t = threadIdx.x;           // 1024 threads
    if (t < C) sa[t] = INT_MAX;
    __syncthreads();
    for (int i = t; i < N; i += 1024) atomicMin(&sa[labels[i]], i);
    __syncthreads();
    if (t < C) anchor[t] = sa[t];
    if (t == 0) *counter = 0u;
}

// one wave per row: fp16 convert + sq[i] + ap[i] (fp32 exact)
__global__ void k_prep(const float* __restrict__ x, const int* __restrict__ labels,
                       const int* __restrict__ anchor, _Float16* __restrict__ xh,
                       float* __restrict__ sq, float* __restrict__ ap) {
    int row = (blockIdx.x * blockDim.x + threadIdx.x) >> 6;
    int lane = threadIdx.x & 63;
    int a = anchor[labels[row]];
    float2 v  = ((const float2*)(x + (size_t)row * D))[lane];
    float2 va = ((const float2*)(x + (size_t)a   * D))[lane];
    half2v h; h[0] = (_Float16)v.x; h[1] = (_Float16)v.y;
    *(half2v*)(xh + (size_t)row * D + lane * 2) = h;
    float s  = v.x * v.x + v.y * v.y;
    float sa = va.x * va.x + va.y * va.y;
    float dp = v.x * va.x + v.y * va.y;
#pragma unroll
    for (int off = 32; off; off >>= 1) {
        s  += __shfl_down(s,  off);
        sa += __shfl_down(sa, off);
        dp += __shfl_down(dp, off);
    }
    if (lane == 0) {
        sq[row] = s;
        ap[row] = sa + s - 2.0f * dp;
    }
}

// ---------------- fused term1+term2: dual-Gram MFMA, 128x64 tile, 3 blocks/CU ----------------

__launch_bounds__(256, 3)
__global__ void k_fused(const _Float16* __restrict__ xh, const int* __restrict__ labels,
                        const int* __restrict__ anchor, const float* __restrict__ sq,
                        const float* __restrict__ ap, float* __restrict__ partials,
                        unsigned int* __restrict__ counter, float* __restrict__ out) {
    __shared__ __align__(16) _Float16 As [BI * SL];   // rows i0..
    __shared__ __align__(16) _Float16 A2s[BI * SL];   // anchor rows of lab(i0..)
    __shared__ __align__(16) _Float16 Bs [BJ * SL];   // rows j0..
    __shared__ float4 rowE[BI];    // (e2 = ap+a/2-sq_i, e1 = ap+a/2-sq_a, lab bits, -)
    __shared__ float2 colJ[BJ];    // (sq_j, lab_j bits)
    __shared__ int sAnc[BI];

    const int i0 = blockIdx.x * BI;
    const int j0 = blockIdx.y * BJ;
    const int tid = threadIdx.x;
    const int lane = tid & 63, w = tid >> 6;
    const int m = lane & 31, q = lane >> 5;

    if (tid < BI) {
        int i = i0 + tid;
        int li = labels[i];
        int a = anchor[li];
        sAnc[tid] = a;
        float e2, e1;
        if (i == a) { e2 = -1e30f; e1 = -1e30f; }   // anchors are not positives
        else {
            float base = ap[i] + HALFA;
            e2 = base - sq[i];
            e1 = base - sq[a];
        }
        rowE[tid] = make_float4(e2, e1, __int_as_float(li), 0.f);
    } else if (tid < BI + BJ) {
        int t = tid - BI;
        int j = j0 + t;
        colJ[t] = make_float2(sq[j], __int_as_float(labels[j]));
    }

    // wave w: i-rows [32w, 32w+32), all 64 j-cols. acc[cb] = Gram2, acc2[cb] = anchor Gram
    floatx16 acc[2], acc2[2];
    acc[0] = zerov(); acc[1] = zerov(); acc2[0] = zerov(); acc2[1] = zerov();

    const _Float16* Abase = &As [(w * 32 + m) * SL + q * 8];
    const _Float16* Cbase = &A2s[(w * 32 + m) * SL + q * 8];
    const _Float16* Bbase = &Bs [m * SL + q * 8];

    for (int kc = 0; kc < D; kc += KC) {
        __syncthreads();
        // stage 320 rows x 64 fp16: 2560 16B-units over 256 threads
#pragma unroll
        for (int it = 0; it < 10; ++it) {
            int f = tid + it * 256;
            int row = f >> 3, g = f & 7;
            const _Float16* src;
            _Float16* dst;
            if (row < BI) {
                src = xh + (size_t)(i0 + row) * D + kc + g * 8;
                dst = &As[row * SL + g * 8];
            } else if (row < 2 * BI) {
                int r = row - BI;
                src = xh + (size_t)sAnc[r] * D + kc + g * 8;
                dst = &A2s[r * SL + g * 8];
            } else {
                int r = row - 2 * BI;
                src = xh + (size_t)(j0 + r) * D + kc + g * 8;
                dst = &Bs[r * SL + g * 8];
            }
            *(half8*)dst = *(const half8*)src;
        }
        __syncthreads();
#pragma unroll
        for (int ks = 0; ks < KC; ks += 16) {
            half8 a0 = *(const half8*)(Abase + ks);
            half8 c0 = *(const half8*)(Cbase + ks);
            half8 b0 = *(const half8*)(Bbase + ks);
            half8 b1 = *(const half8*)(Bbase + 32 * SL + ks);
            acc [0] = __builtin_amdgcn_mfma_f32_32x32x16_f16(a0, b0, acc [0], 0, 0, 0);
            acc [1] = __builtin_amdgcn_mfma_f32_32x32x16_f16(a0, b1, acc [1], 0, 0, 0);
            acc2[0] = __builtin_amdgcn_mfma_f32_32x32x16_f16(c0, b0, acc2[0], 0, 0, 0);
            acc2[1] = __builtin_amdgcn_mfma_f32_32x32x16_f16(c0, b1, acc2[1], 0, 0, 0);
        }
    }

    float sqj[2]; int labj[2];
#pragma unroll
    for (int cb = 0; cb < 2; ++cb) {
        float2 cj = colJ[cb * 32 + m];
        sqj[cb] = cj.x; labj[cb] = __float_as_int(cj.y);
    }

    // hinge band-pass: u = 2*dot + e' - sq_j; contributes (u + a/2) iff |u| < a/2
    float local = 0.f;
#pragma unroll
    for (int rr = 0; rr < 16; ++rr) {
        int row = w * 32 + (rr & 3) + 8 * (rr >> 2) + 4 * q;
        float4 re = rowE[row];
        int labi = __float_as_int(re.z);
#pragma unroll
        for (int cb = 0; cb < 2; ++cb) {
            if (labi != labj[cb]) {
                float u2 = fmaf(2.f, acc [cb][rr], re.x - sqj[cb]);
                if (__builtin_fabsf(u2) < HALFA) local += u2 + HALFA;
                float u1 = fmaf(2.f, acc2[cb][rr], re.y - sqj[cb]);
                if (__builtin_fabsf(u1) < HALFA) local += u1 + HALFA;
            }
        }
    }

    // block reduce -> per-block partial; last finished block reduces all partials
#pragma unroll
    for (int off = 32; off; off >>= 1) local += __shfl_down(local, off);
    __shared__ float wsum[4];
    __shared__ int slast;
    if (lane == 0) wsum[w] = local;
    __syncthreads();
    const int bid = blockIdx.y * gridDim.x + blockIdx.x;
    if (tid == 0) {
        float p = wsum[0] + wsum[1] + wsum[2] + wsum[3];
        __hip_atomic_store(&partials[bid], p, __ATOMIC_RELAXED, __HIP_MEMORY_SCOPE_AGENT);
        __threadfence();
        unsigned int old = __hip_atomic_fetch_add(counter, 1u, __ATOMIC_ACQ_REL,
                                                  __HIP_MEMORY_SCOPE_AGENT);
        slast = (old == (unsigned int)(NBLK - 1)) ? 1 : 0;
    }
    __syncthreads();
    if (slast) {
        __threadfence();
        double s = 0.0;
        for (int t = tid; t < NBLK; t += 256)
            s += (double)__hip_atomic_load(&partials[t], __ATOMIC_RELAXED,
                                           __HIP_MEMORY_SCOPE_AGENT);
#pragma unroll
        for (int off = 32; off; off >>= 1) s += __shfl_down(s, off);
        __shared__ double dsum[4];
        if (lane == 0) dsum[w] = s;
        __syncthreads();
        if (tid == 0) out[0] = (float)(dsum[0] + dsum[1] + dsum[2] + dsum[3]);
    }
}

// ---------------- launch ----------------

extern "C" void kernel_launch(void* const* d_in, const int* in_sizes, int n_in,
                              void* d_out, int out_size, void* d_ws, size_t ws_size,
                              hipStream_t stream) {
    const float* x = (const float*)d_in[0];
    const int* labels = (const int*)d_in[1];
    float* out = (float*)d_out;

    char* p = (char*)d_ws;
    int* anchor = (int*)p;            p += C * 4;
    float* sq = (float*)p;            p += N * 4;
    float* ap = (float*)p;            p += N * 4;
    float* partials = (float*)p;      p += NBLK * 4;
    unsigned int* counter = (unsigned int*)p;  p += 256;
    p = (char*)(((uintptr_t)p + 255) & ~(uintptr_t)255);
    _Float16* xh = (_Float16*)p;      // N*D*2 bytes

    k_anchor<<<1, 1024, 0, stream>>>(labels, anchor, counter);
    k_prep<<<N / 4, 256, 0, stream>>>(x, labels, anchor, xh, sq, ap);
    dim3 g(N / BI, N / BJ);
    k_fused<<<g, 256, 0, stream>>>(xh, labels, anchor, sq, ap, partials, counter, out);
}

// Round 7
// 166.106 us; speedup vs baseline: 2.2875x; 2.2875x over previous
//
#include <hip/hip_runtime.h>
#include <limits.h>
#include <stdint.h>

#define ALPHA 0.2f
#define HALFA 0.1f
static constexpr int N = 8192;
static constexpr int D = 128;
static constexpr int C = 512;
static constexpr int BT = 128;          // block tile (i and j) -- R4-proven
static constexpr int KC = 32;           // k-chunk in fp16 elems -- R4-proven
static constexpr int SL = 40;           // LDS row stride in fp16 (32 + 8 pad) -- R4-proven
static constexpr int NBLK = (N / BT) * (N / BT);   // 4096
static constexpr int ABIAS = 0x40000000; // anchor encode: atomicMax(ABIAS - i); poison 0xAA... < all encodings

using half8   = __attribute__((ext_vector_type(8))) _Float16;
using half2v  = __attribute__((ext_vector_type(2))) _Float16;
using floatx16 = __attribute__((ext_vector_type(16))) float;

__device__ __forceinline__ floatx16 zerov() { floatx16 v = {0.f}; return v; }

union H8 { half8 v; half2v h2[4]; };

// ---------------- prep: fp16 convert + sq + anchor (no init kernel needed) ----------------
// anchor[] lives in 0xAA-poisoned ws: 0xAAAAAAAA as int is negative, ABIAS - i ~ 2^30 always wins.

__global__ void k_prep(const float* __restrict__ x, const int* __restrict__ labels,
                       _Float16* __restrict__ xh, float* __restrict__ sq,
                       int* __restrict__ anchor) {
    int row = (blockIdx.x * blockDim.x + threadIdx.x) >> 6;
    int lane = threadIdx.x & 63;
    float2 v = ((const float2*)(x + (size_t)row * D))[lane];
    half2v h; h[0] = (_Float16)v.x; h[1] = (_Float16)v.y;
    *(half2v*)(xh + (size_t)row * D + lane * 2) = h;
    float s = v.x * v.x + v.y * v.y;
#pragma unroll
    for (int off = 32; off; off >>= 1) s += __shfl_down(s, off);
    if (lane == 0) {
        sq[row] = s;
        atomicMax(&anchor[labels[row]], ABIAS - row);   // min-index via max-encode
    }
}

// ---------------- fused term1+term2: dual-Gram MFMA (R4 body) + in-block ap ----------------

__launch_bounds__(256)
__global__ void k_fused(const _Float16* __restrict__ xh, const int* __restrict__ labels,
                        const int* __restrict__ anchor, const float* __restrict__ sq,
                        float* __restrict__ partials) {
    __shared__ __align__(16) _Float16 As [BT * SL];   // rows i0..
    __shared__ __align__(16) _Float16 A2s[BT * SL];   // anchor rows of lab(i0..)
    __shared__ __align__(16) _Float16 Bs [BT * SL];   // rows j0..
    __shared__ float4 rowE[BT];    // (e2 = ap+a/2-sq_i, e1 = ap+a/2-sq_a, lab bits, -)
    __shared__ float2 colJ[BT];    // (sq_j, lab_j bits)
    __shared__ float2 sMeta[BT];   // (sq_i, sq_a)
    __shared__ int sAnc[BT];
    __shared__ int sLab[BT];

    const int i0 = blockIdx.x * BT;
    const int j0 = blockIdx.y * BT;
    const int tid = threadIdx.x;
    const int lane = tid & 63, w = tid >> 6;
    const int wr = w >> 1, wc = w & 1;
    const int m = lane & 31, q = lane >> 5;

    if (tid < BT) {
        int i = i0 + tid;
        int li = labels[i];
        int a = ABIAS - anchor[li];
        sAnc[tid] = a;
        sLab[tid] = li;
        sMeta[tid] = make_float2(sq[i], sq[a]);
    } else {
        int t = tid - BT;
        int j = j0 + t;
        colJ[t] = make_float2(sq[j], __int_as_float(labels[j]));
    }
    __syncthreads();   // sAnc/sMeta ready

    // in-block ap: row r = tid>>1, half hh = tid&1 covers 64 fp16 elems
    {
        int r = tid >> 1, hh = tid & 1;
        int a = sAnc[r];
        const half8* pi = (const half8*)(xh + (size_t)(i0 + r) * D + hh * 64);
        const half8* pa = (const half8*)(xh + (size_t)a * D + hh * 64);
        float apdot = 0.f;
#pragma unroll
        for (int u = 0; u < 8; ++u) {
            H8 va, vb; va.v = pi[u]; vb.v = pa[u];
#pragma unroll
            for (int e = 0; e < 4; ++e) {
#if __has_builtin(__builtin_amdgcn_fdot2)
                apdot = __builtin_amdgcn_fdot2(va.h2[e], vb.h2[e], apdot, false);
#else
                apdot += (float)va.h2[e][0] * (float)vb.h2[e][0]
                       + (float)va.h2[e][1] * (float)vb.h2[e][1];
#endif
            }
        }
        apdot += __shfl_xor(apdot, 1);
        if (hh == 0) {
            float2 mt = sMeta[r];
            float apv = mt.x + mt.y - 2.f * apdot;   // D(i, anchor_i)
            float e2, e1;
            if (i0 + r == sAnc[r]) { e2 = -1e30f; e1 = -1e30f; }  // anchors aren't positives
            else {
                float base = apv + HALFA;
                e2 = base - mt.x;
                e1 = base - mt.y;
            }
            rowE[r] = make_float4(e2, e1, __int_as_float(sLab[r]), 0.f);
        }
    }
    // rowE visibility to all waves is covered by the K-loop's first __syncthreads()

    floatx16 acc[2][2], acc2[2][2];
#pragma unroll
    for (int a = 0; a < 2; ++a)
#pragma unroll
        for (int b = 0; b < 2; ++b) { acc[a][b] = zerov(); acc2[a][b] = zerov(); }

    const _Float16* Abase = &As [(wr * 64 + m) * SL + q * 8];
    const _Float16* Cbase = &A2s[(wr * 64 + m) * SL + q * 8];
    const _Float16* Bbase = &Bs [(wc * 64 + m) * SL + q * 8];

    for (int kc = 0; kc < D; kc += KC) {
        __syncthreads();
#pragma unroll
        for (int it = 0; it < 2; ++it) {
            int f = tid + it * 256;
            int row = f >> 2, g = f & 3;
            size_t go = (size_t)kc + g * 8;
            half8 v = *(const half8*)(xh + (size_t)(i0 + row) * D + go);
            *(half8*)(&As[row * SL + g * 8]) = v;
            half8 u = *(const half8*)(xh + (size_t)(j0 + row) * D + go);
            *(half8*)(&Bs[row * SL + g * 8]) = u;
            half8 t = *(const half8*)(xh + (size_t)sAnc[row] * D + go);
            *(half8*)(&A2s[row * SL + g * 8]) = t;
        }
        __syncthreads();
#pragma unroll
        for (int ks = 0; ks < KC; ks += 16) {
            half8 a0 = *(const half8*)(Abase + ks);
            half8 a1 = *(const half8*)(Abase + 32 * SL + ks);
            half8 c0 = *(const half8*)(Cbase + ks);
            half8 c1 = *(const half8*)(Cbase + 32 * SL + ks);
            half8 b0 = *(const half8*)(Bbase + ks);
            half8 b1 = *(const half8*)(Bbase + 32 * SL + ks);
            acc [0][0] = __builtin_amdgcn_mfma_f32_32x32x16_f16(a0, b0, acc [0][0], 0, 0, 0);
            acc [0][1] = __builtin_amdgcn_mfma_f32_32x32x16_f16(a0, b1, acc [0][1], 0, 0, 0);
            acc [1][0] = __builtin_amdgcn_mfma_f32_32x32x16_f16(a1, b0, acc [1][0], 0, 0, 0);
            acc [1][1] = __builtin_amdgcn_mfma_f32_32x32x16_f16(a1, b1, acc [1][1], 0, 0, 0);
            acc2[0][0] = __builtin_amdgcn_mfma_f32_32x32x16_f16(c0, b0, acc2[0][0], 0, 0, 0);
            acc2[0][1] = __builtin_amdgcn_mfma_f32_32x32x16_f16(c0, b1, acc2[0][1], 0, 0, 0);
            acc2[1][0] = __builtin_amdgcn_mfma_f32_32x32x16_f16(c1, b0, acc2[1][0], 0, 0, 0);
            acc2[1][1] = __builtin_amdgcn_mfma_f32_32x32x16_f16(c1, b1, acc2[1][1], 0, 0, 0);
        }
    }

    float sqj[2]; int labj[2];
#pragma unroll
    for (int tn = 0; tn < 2; ++tn) {
        float2 cj = colJ[wc * 64 + tn * 32 + m];
        sqj[tn] = cj.x; labj[tn] = __float_as_int(cj.y);
    }

    // hinge band-pass: u = 2*dot + e' - sq_j; contributes (u + a/2) iff |u| < a/2
    float local = 0.f;
#pragma unroll
    for (int tm = 0; tm < 2; ++tm) {
        int rbase = wr * 64 + tm * 32 + 4 * q;
#pragma unroll
        for (int rr = 0; rr < 16; ++rr) {
            int row = rbase + (rr & 3) + 8 * (rr >> 2);
            float4 re = rowE[row];
            int labi = __float_as_int(re.z);
#pragma unroll
            for (int tn = 0; tn < 2; ++tn) {
                if (labi != labj[tn]) {
                    float u2 = fmaf(2.f, acc [tm][tn][rr], re.x - sqj[tn]);
                    if (__builtin_fabsf(u2) < HALFA) local += u2 + HALFA;
                    float u1 = fmaf(2.f, acc2[tm][tn][rr], re.y - sqj[tn]);
                    if (__builtin_fabsf(u1) < HALFA) local += u1 + HALFA;
                }
            }
        }
    }

    // block reduce -> plain per-block partial store (no contended atomics)
#pragma unroll
    for (int off = 32; off; off >>= 1) local += __shfl_down(local, off);
    __shared__ float wsum[4];
    if (lane == 0) wsum[w] = local;
    __syncthreads();
    if (tid == 0)
        partials[blockIdx.y * gridDim.x + blockIdx.x] = wsum[0] + wsum[1] + wsum[2] + wsum[3];
}

__global__ void k_final(const float* __restrict__ partials, float* __restrict__ out) {
    __shared__ double sred[4];
    int tid = threadIdx.x, lane = tid & 63;
    double s = 0.0;
    for (int t = tid; t < NBLK; t += 256) s += (double)partials[t];
#pragma unroll
    for (int off = 32; off; off >>= 1) s += __shfl_down(s, off);
    if (lane == 0) sred[tid >> 6] = s;
    __syncthreads();
    if (tid == 0) out[0] = (float)(sred[0] + sred[1] + sred[2] + sred[3]);
}

// ---------------- launch ----------------

extern "C" void kernel_launch(void* const* d_in, const int* in_sizes, int n_in,
                              void* d_out, int out_size, void* d_ws, size_t ws_size,
                              hipStream_t stream) {
    const float* x = (const float*)d_in[0];
    const int* labels = (const int*)d_in[1];
    float* out = (float*)d_out;

    char* p = (char*)d_ws;
    int* anchor = (int*)p;            p += C * 4;
    float* sq = (float*)p;            p += N * 4;
    float* partials = (float*)p;      p += NBLK * 4;
    p = (char*)(((uintptr_t)p + 255) & ~(uintptr_t)255);
    _Float16* xh = (_Float16*)p;      // N*D*2 bytes

    k_prep<<<N / 4, 256, 0, stream>>>(x, labels, xh, sq, anchor);
    dim3 g(N / BT, N / BT);
    k_fused<<<g, 256, 0, stream>>>(xh, labels, anchor, sq, partials);
    k_final<<<1, 256, 0, stream>>>(partials, out);
}

// Round 8
// 163.619 us; speedup vs baseline: 2.3223x; 1.0152x over previous
//
#include <hip/hip_runtime.h>
#include <limits.h>
#include <stdint.h>

#define ALPHA 0.2f
#define HALFA 0.1f
static constexpr int N = 8192;
static constexpr int D = 128;
static constexpr int C = 512;
static constexpr int BT = 128;          // block tile (i and j)
static constexpr int KC = 32;           // k-chunk in fp16 elems (R4-proven)
static constexpr int SL = 40;           // LDS row stride in fp16 (32 + 8 pad, R4-proven)
static constexpr int ABIAS = 0x40000000; // anchor encode: atomicMax(ABIAS - i); 0xAA poison < all encodings

using half8   = __attribute__((ext_vector_type(8))) _Float16;
using half2v  = __attribute__((ext_vector_type(2))) _Float16;
using floatx16 = __attribute__((ext_vector_type(16))) float;

__device__ __forceinline__ floatx16 zerov() { floatx16 v = {0.f}; return v; }

// ---------------- prep: fp16 convert + sq + anchor + zero out ----------------

__global__ void k_prep(const float* __restrict__ x, const int* __restrict__ labels,
                       _Float16* __restrict__ xh, float* __restrict__ sq,
                       int* __restrict__ anchor, float* __restrict__ out) {
    int row = (blockIdx.x * blockDim.x + threadIdx.x) >> 6;
    int lane = threadIdx.x & 63;
    float2 v = ((const float2*)(x + (size_t)row * D))[lane];
    half2v h; h[0] = (_Float16)v.x; h[1] = (_Float16)v.y;
    *(half2v*)(xh + (size_t)row * D + lane * 2) = h;
    float s = v.x * v.x + v.y * v.y;
#pragma unroll
    for (int off = 32; off; off >>= 1) s += __shfl_down(s, off);
    if (lane == 0) {
        sq[row] = s;
        atomicMax(&anchor[labels[row]], ABIAS - row);   // min-index via max-encode
    }
    if (blockIdx.x == 0 && threadIdx.x == 0) out[0] = 0.f;
}

// ---------------- table: T[c][j] = D(anchor_c, x_j), plus ap[j] = T[lab_j][j] ----------------

__launch_bounds__(256)
__global__ void k_table(const _Float16* __restrict__ xh, const int* __restrict__ labels,
                        const int* __restrict__ anchor, const float* __restrict__ sq,
                        float* __restrict__ T, float* __restrict__ ap) {
    __shared__ __align__(16) _Float16 As[BT * SL];   // anchor rows c0..
    __shared__ __align__(16) _Float16 Bs[BT * SL];   // rows j0..
    __shared__ float sSqA[BT];
    __shared__ float2 colJ[BT];    // (sq_j, lab_j bits)
    __shared__ int sAnc[BT];

    const int c0 = blockIdx.x * BT;
    const int j0 = blockIdx.y * BT;
    const int tid = threadIdx.x;
    const int lane = tid & 63, w = tid >> 6;
    const int wr = w >> 1, wc = w & 1;
    const int m = lane & 31, q = lane >> 5;

    if (tid < BT) {
        int c = c0 + tid;
        int raw = anchor[c];
        int a = (raw > 0) ? (ABIAS - raw) : 0;   // empty label -> dummy row 0 (never read)
        sAnc[tid] = a;
        sSqA[tid] = sq[a];
    } else {
        int t = tid - BT;
        int j = j0 + t;
        colJ[t] = make_float2(sq[j], __int_as_float(labels[j]));
    }

    floatx16 acc[2][2];
    acc[0][0] = zerov(); acc[0][1] = zerov(); acc[1][0] = zerov(); acc[1][1] = zerov();

    const _Float16* Abase = &As[(wr * 64 + m) * SL + q * 8];
    const _Float16* Bbase = &Bs[(wc * 64 + m) * SL + q * 8];

    for (int kc = 0; kc < D; kc += KC) {
        __syncthreads();
#pragma unroll
        for (int it = 0; it < 2; ++it) {
            int f = tid + it * 256;
            int row = f >> 2, g = f & 3;
            size_t go = (size_t)kc + g * 8;
            half8 v = *(const half8*)(xh + (size_t)sAnc[row] * D + go);
            *(half8*)(&As[row * SL + g * 8]) = v;
            half8 u = *(const half8*)(xh + (size_t)(j0 + row) * D + go);
            *(half8*)(&Bs[row * SL + g * 8]) = u;
        }
        __syncthreads();
#pragma unroll
        for (int ks = 0; ks < KC; ks += 16) {
            half8 a0 = *(const half8*)(Abase + ks);
            half8 a1 = *(const half8*)(Abase + 32 * SL + ks);
            half8 b0 = *(const half8*)(Bbase + ks);
            half8 b1 = *(const half8*)(Bbase + 32 * SL + ks);
            acc[0][0] = __builtin_amdgcn_mfma_f32_32x32x16_f16(a0, b0, acc[0][0], 0, 0, 0);
            acc[0][1] = __builtin_amdgcn_mfma_f32_32x32x16_f16(a0, b1, acc[0][1], 0, 0, 0);
            acc[1][0] = __builtin_amdgcn_mfma_f32_32x32x16_f16(a1, b0, acc[1][0], 0, 0, 0);
            acc[1][1] = __builtin_amdgcn_mfma_f32_32x32x16_f16(a1, b1, acc[1][1], 0, 0, 0);
        }
    }

    float sqj[2]; int labj[2];
#pragma unroll
    for (int tn = 0; tn < 2; ++tn) {
        float2 cj = colJ[wc * 64 + tn * 32 + m];
        sqj[tn] = cj.x; labj[tn] = __float_as_int(cj.y);
    }

#pragma unroll
    for (int tm = 0; tm < 2; ++tm) {
        int rbase = wr * 64 + tm * 32 + 4 * q;
#pragma unroll
        for (int rr = 0; rr < 16; ++rr) {
            int row = rbase + (rr & 3) + 8 * (rr >> 2);
            int c = c0 + row;
            float sqa = sSqA[row];
#pragma unroll
            for (int tn = 0; tn < 2; ++tn) {
                int col = wc * 64 + tn * 32 + m;
                float Dv = fmaf(-2.f, acc[tm][tn][rr], sqa + sqj[tn]);
                T[(size_t)c * N + j0 + col] = Dv;
                if (labj[tn] == c) ap[j0 + col] = Dv;   // ap[j] = D(anchor_{lab_j}, j)
            }
        }
    }
}

// ---------------- fused: term2 Gram + term1 via T-table reads ----------------

__launch_bounds__(256)
__global__ void k_fused(const _Float16* __restrict__ xh, const int* __restrict__ labels,
                        const int* __restrict__ anchor, const float* __restrict__ sq,
                        const float* __restrict__ ap, const float* __restrict__ T,
                        float* __restrict__ out) {
    __shared__ __align__(16) _Float16 As[BT * SL];   // rows i0..
    __shared__ __align__(16) _Float16 Bs[BT * SL];   // rows j0..
    __shared__ float4 rowE[BT];    // (e2 = ap+a/2-sq_i, e1p = ap+a/2, lab bits, -)
    __shared__ float2 colJ[BT];    // (sq_j, lab_j bits)

    const int i0 = blockIdx.x * BT;
    const int j0 = blockIdx.y * BT;
    const int tid = threadIdx.x;
    const int lane = tid & 63, w = tid >> 6;
    const int wr = w >> 1, wc = w & 1;
    const int m = lane & 31, q = lane >> 5;

    if (tid < BT) {
        int i = i0 + tid;
        int li = labels[i];
        int a = ABIAS - anchor[li];
        float e2, e1p;
        if (i == a) { e2 = -1e30f; e1p = -1e30f; }   // anchors are not positives
        else {
            e1p = ap[i] + HALFA;
            e2 = e1p - sq[i];
        }
        rowE[tid] = make_float4(e2, e1p, __int_as_float(li), 0.f);
    } else {
        int t = tid - BT;
        int j = j0 + t;
        colJ[t] = make_float2(sq[j], __int_as_float(labels[j]));
    }

    floatx16 acc[2][2];
    acc[0][0] = zerov(); acc[0][1] = zerov(); acc[1][0] = zerov(); acc[1][1] = zerov();

    const _Float16* Abase = &As[(wr * 64 + m) * SL + q * 8];
    const _Float16* Bbase = &Bs[(wc * 64 + m) * SL + q * 8];

    for (int kc = 0; kc < D; kc += KC) {
        __syncthreads();
#pragma unroll
        for (int it = 0; it < 2; ++it) {
            int f = tid + it * 256;
            int row = f >> 2, g = f & 3;
            size_t go = (size_t)kc + g * 8;
            half8 v = *(const half8*)(xh + (size_t)(i0 + row) * D + go);
            *(half8*)(&As[row * SL + g * 8]) = v;
            half8 u = *(const half8*)(xh + (size_t)(j0 + row) * D + go);
            *(half8*)(&Bs[row * SL + g * 8]) = u;
        }
        __syncthreads();
#pragma unroll
        for (int ks = 0; ks < KC; ks += 16) {
            half8 a0 = *(const half8*)(Abase + ks);
            half8 a1 = *(const half8*)(Abase + 32 * SL + ks);
            half8 b0 = *(const half8*)(Bbase + ks);
            half8 b1 = *(const half8*)(Bbase + 32 * SL + ks);
            acc[0][0] = __builtin_amdgcn_mfma_f32_32x32x16_f16(a0, b0, acc[0][0], 0, 0, 0);
            acc[0][1] = __builtin_amdgcn_mfma_f32_32x32x16_f16(a0, b1, acc[0][1], 0, 0, 0);
            acc[1][0] = __builtin_amdgcn_mfma_f32_32x32x16_f16(a1, b0, acc[1][0], 0, 0, 0);
            acc[1][1] = __builtin_amdgcn_mfma_f32_32x32x16_f16(a1, b1, acc[1][1], 0, 0, 0);
        }
    }

    float sqj[2]; int labj[2];
#pragma unroll
    for (int tn = 0; tn < 2; ++tn) {
        float2 cj = colJ[wc * 64 + tn * 32 + m];
        sqj[tn] = cj.x; labj[tn] = __float_as_int(cj.y);
    }

    // term2: u2 = 2*dot + e2 - sq_j, contribute u2+a/2 iff |u2| < a/2
    // term1: u1 = e1p - T[lab_i][j], contribute u1+a/2 iff |u1| < a/2
    float local = 0.f;
#pragma unroll
    for (int tm = 0; tm < 2; ++tm) {
        int rbase = wr * 64 + tm * 32 + 4 * q;
#pragma unroll
        for (int rr = 0; rr < 16; ++rr) {
            int row = rbase + (rr & 3) + 8 * (rr >> 2);
            float4 re = rowE[row];
            int labi = __float_as_int(re.z);
            const float* tptr = T + (size_t)labi * N + j0 + wc * 64 + m;
            float t0 = tptr[0];
            float t1 = tptr[32];
#pragma unroll
            for (int tn = 0; tn < 2; ++tn) {
                if (labi != labj[tn]) {
                    float u2 = fmaf(2.f, acc[tm][tn][rr], re.x - sqj[tn]);
                    if (__builtin_fabsf(u2) < HALFA) local += u2 + HALFA;
                    float u1 = re.y - (tn ? t1 : t0);
                    if (__builtin_fabsf(u1) < HALFA) local += u1 + HALFA;
                }
            }
        }
    }

    // block reduce -> one fire-and-forget float atomic
#pragma unroll
    for (int off = 32; off; off >>= 1) local += __shfl_down(local, off);
    __shared__ float wsum[4];
    if (lane == 0) wsum[w] = local;
    __syncthreads();
    if (tid == 0) atomicAdd(out, wsum[0] + wsum[1] + wsum[2] + wsum[3]);
}

// ---------------- launch ----------------

extern "C" void kernel_launch(void* const* d_in, const int* in_sizes, int n_in,
                              void* d_out, int out_size, void* d_ws, size_t ws_size,
                              hipStream_t stream) {
    const float* x = (const float*)d_in[0];
    const int* labels = (const int*)d_in[1];
    float* out = (float*)d_out;

    char* p = (char*)d_ws;
    int* anchor = (int*)p;            p += C * 4;
    float* sq = (float*)p;            p += N * 4;
    float* ap = (float*)p;            p += N * 4;
    p = (char*)(((uintptr_t)p + 255) & ~(uintptr_t)255);
    float* T = (float*)p;             p += (size_t)C * N * 4;   // 16 MB
    _Float16* xh = (_Float16*)p;      // N*D*2 = 2 MB

    k_prep<<<N / 4, 256, 0, stream>>>(x, labels, xh, sq, anchor, out);
    dim3 gt(C / BT, N / BT);
    k_table<<<gt, 256, 0, stream>>>(xh, labels, anchor, sq, T, ap);
    dim3 g(N / BT, N / BT);
    k_fused<<<g, 256, 0, stream>>>(xh, labels, anchor, sq, ap, T, out);
}

// Round 9
// 161.093 us; speedup vs baseline: 2.3587x; 1.0157x over previous
//
#include <hip/hip_runtime.h>
#include <limits.h>
#include <stdint.h>

#define ALPHA 0.2f
#define HALFA 0.1f
static constexpr int N = 8192;
static constexpr int D = 128;
static constexpr int C = 512;
static constexpr int BT = 128;          // block tile (i and j)
static constexpr int KC = 32;           // k-chunk in fp16 elems (R4-proven)
static constexpr int SL = 40;           // LDS row stride in fp16 (32 + 8 pad, R4-proven)
static constexpr int NB = N / BT;       // 64
static constexpr int NTRI = NB * (NB + 1) / 2;   // 2080 upper-triangle blocks
static constexpr int ABIAS = 0x40000000; // anchor encode: atomicMax(ABIAS - i); 0xAA poison < all

using half8   = __attribute__((ext_vector_type(8))) _Float16;
using half2v  = __attribute__((ext_vector_type(2))) _Float16;
using floatx16 = __attribute__((ext_vector_type(16))) float;

__device__ __forceinline__ floatx16 zerov() { floatx16 v = {0.f}; return v; }

// ---------------- prep: fp16 convert + sq + anchor ----------------

__global__ void k_prep(const float* __restrict__ x, const int* __restrict__ labels,
                       _Float16* __restrict__ xh, float* __restrict__ sq,
                       int* __restrict__ anchor) {
    int row = (blockIdx.x * blockDim.x + threadIdx.x) >> 6;
    int lane = threadIdx.x & 63;
    float2 v = ((const float2*)(x + (size_t)row * D))[lane];
    half2v h; h[0] = (_Float16)v.x; h[1] = (_Float16)v.y;
    *(half2v*)(xh + (size_t)row * D + lane * 2) = h;
    float s = v.x * v.x + v.y * v.y;
#pragma unroll
    for (int off = 32; off; off >>= 1) s += __shfl_down(s, off);
    if (lane == 0) {
        sq[row] = s;
        atomicMax(&anchor[labels[row]], ABIAS - row);   // min-index via max-encode
    }
}

// ---------------- perm: counting-sort permutation by label (1 block) ----------------

__global__ void k_perm(const int* __restrict__ labels, int* __restrict__ perm) {
    __shared__ int scnt[C];
    __shared__ int scur[C];
    int t = threadIdx.x;   // 1024
    if (t < C) scnt[t] = 0;
    __syncthreads();
    for (int i = t; i < N; i += 1024) atomicAdd(&scnt[labels[i]], 1);
    __syncthreads();
    int myc = (t < C) ? scnt[t] : 0;
    // Hillis-Steele inclusive scan over C entries
    for (int off = 1; off < C; off <<= 1) {
        int v = 0;
        if (t < C) { v = scnt[t]; if (t >= off) v += scnt[t - off]; }
        __syncthreads();
        if (t < C) scnt[t] = v;
        __syncthreads();
    }
    if (t < C) scur[t] = scnt[t] - myc;   // exclusive offsets
    __syncthreads();
    for (int i = t; i < N; i += 1024) {
        int c = labels[i];
        int pos = atomicAdd(&scur[c], 1);
        perm[pos] = i;
    }
}

// ---------------- table: T[c][t] = D(anchor_c, x_perm[t]); apP[t] = T[lab_t][t] ----------------

__launch_bounds__(256)
__global__ void k_table(const _Float16* __restrict__ xh, const int* __restrict__ labels,
                        const int* __restrict__ anchor, const float* __restrict__ sq,
                        const int* __restrict__ perm, float* __restrict__ T,
                        float* __restrict__ apP) {
    __shared__ __align__(16) _Float16 As[BT * SL];   // anchor rows c0..
    __shared__ __align__(16) _Float16 Bs[BT * SL];   // permuted rows j0..
    __shared__ float sSqA[BT];
    __shared__ float2 colJ[BT];    // (sq_j, lab_j bits)
    __shared__ int sAnc[BT];
    __shared__ int sPj[BT];

    const int c0 = blockIdx.x * BT;
    const int j0 = blockIdx.y * BT;
    const int tid = threadIdx.x;
    const int lane = tid & 63, w = tid >> 6;
    const int wr = w >> 1, wc = w & 1;
    const int m = lane & 31, q = lane >> 5;

    if (tid < BT) {
        int c = c0 + tid;
        int raw = anchor[c];
        int a = (raw > 0) ? (ABIAS - raw) : 0;   // empty label -> dummy row (never read)
        sAnc[tid] = a;
        sSqA[tid] = sq[a];
    } else {
        int t = tid - BT;
        int j = perm[j0 + t];
        sPj[t] = j;
        colJ[t] = make_float2(sq[j], __int_as_float(labels[j]));
    }

    floatx16 acc[2][2];
    acc[0][0] = zerov(); acc[0][1] = zerov(); acc[1][0] = zerov(); acc[1][1] = zerov();

    const _Float16* Abase = &As[(wr * 64 + m) * SL + q * 8];
    const _Float16* Bbase = &Bs[(wc * 64 + m) * SL + q * 8];

    for (int kc = 0; kc < D; kc += KC) {
        __syncthreads();
#pragma unroll
        for (int it = 0; it < 2; ++it) {
            int f = tid + it * 256;
            int row = f >> 2, g = f & 3;
            size_t go = (size_t)kc + g * 8;
            half8 v = *(const half8*)(xh + (size_t)sAnc[row] * D + go);
            *(half8*)(&As[row * SL + g * 8]) = v;
            half8 u = *(const half8*)(xh + (size_t)sPj[row] * D + go);
            *(half8*)(&Bs[row * SL + g * 8]) = u;
        }
        __syncthreads();
#pragma unroll
        for (int ks = 0; ks < KC; ks += 16) {
            half8 a0 = *(const half8*)(Abase + ks);
            half8 a1 = *(const half8*)(Abase + 32 * SL + ks);
            half8 b0 = *(const half8*)(Bbase + ks);
            half8 b1 = *(const half8*)(Bbase + 32 * SL + ks);
            acc[0][0] = __builtin_amdgcn_mfma_f32_32x32x16_f16(a0, b0, acc[0][0], 0, 0, 0);
            acc[0][1] = __builtin_amdgcn_mfma_f32_32x32x16_f16(a0, b1, acc[0][1], 0, 0, 0);
            acc[1][0] = __builtin_amdgcn_mfma_f32_32x32x16_f16(a1, b0, acc[1][0], 0, 0, 0);
            acc[1][1] = __builtin_amdgcn_mfma_f32_32x32x16_f16(a1, b1, acc[1][1], 0, 0, 0);
        }
    }

    float sqj[2]; int labj[2];
#pragma unroll
    for (int tn = 0; tn < 2; ++tn) {
        float2 cj = colJ[wc * 64 + tn * 32 + m];
        sqj[tn] = cj.x; labj[tn] = __float_as_int(cj.y);
    }

#pragma unroll
    for (int tm = 0; tm < 2; ++tm) {
        int rbase = wr * 64 + tm * 32 + 4 * q;
#pragma unroll
        for (int rr = 0; rr < 16; ++rr) {
            int row = rbase + (rr & 3) + 8 * (rr >> 2);
            int c = c0 + row;
            float sqa = sSqA[row];
#pragma unroll
            for (int tn = 0; tn < 2; ++tn) {
                int col = wc * 64 + tn * 32 + m;
                float Dv = fmaf(-2.f, acc[tm][tn][rr], sqa + sqj[tn]);
                T[(size_t)c * N + j0 + col] = Dv;
                if (labj[tn] == c) apP[j0 + col] = Dv;
            }
        }
    }
}

// ---------------- fused: symmetric Gram (upper-triangle), dual-orientation epilogue ----------------

__launch_bounds__(256)
__global__ void k_fused(const _Float16* __restrict__ xh, const int* __restrict__ labels,
                        const int* __restrict__ anchor, const float* __restrict__ sq,
                        const float* __restrict__ apP, const int* __restrict__ perm,
                        const float* __restrict__ T, float* __restrict__ out) {
    __shared__ __align__(16) _Float16 As[BT * SL];
    __shared__ __align__(16) _Float16 Bs[BT * SL];
    __shared__ float4 rowE[BT];    // (e2i, e1pi, labi bits, sq_i)
    __shared__ float4 colE[BT];    // (e2j, e1pj, labj bits, sq_j)
    __shared__ int sPi[BT], sPj[BT];

    // decode upper-triangle block index
    int rem = blockIdx.x, br = 0;
    while (rem >= NB - br) { rem -= NB - br; ++br; }
    const int bc = br + rem;
    const int i0 = br * BT;
    const int j0 = bc * BT;
    const bool diag = (br == bc);

    const int tid = threadIdx.x;
    const int lane = tid & 63, w = tid >> 6;
    const int wr = w >> 1, wc = w & 1;
    const int m = lane & 31, q = lane >> 5;

    if (tid < BT) {
        int i = perm[i0 + tid];
        sPi[tid] = i;
        int li = labels[i];
        int a = ABIAS - anchor[li];
        float sqi = sq[i];
        float e2, e1p;
        if (i == a) { e2 = -1e30f; e1p = -1e30f; }
        else { e1p = apP[i0 + tid] + HALFA; e2 = e1p - sqi; }
        rowE[tid] = make_float4(e2, e1p, __int_as_float(li), sqi);
    } else {
        int t = tid - BT;
        int j = perm[j0 + t];
        sPj[t] = j;
        int lj = labels[j];
        int a = ABIAS - anchor[lj];
        float sqj = sq[j];
        float e2, e1p;
        if (j == a) { e2 = -1e30f; e1p = -1e30f; }
        else { e1p = apP[j0 + t] + HALFA; e2 = e1p - sqj; }
        colE[t] = make_float4(e2, e1p, __int_as_float(lj), sqj);
    }

    floatx16 acc[2][2];
    acc[0][0] = zerov(); acc[0][1] = zerov(); acc[1][0] = zerov(); acc[1][1] = zerov();

    const _Float16* Abase = &As[(wr * 64 + m) * SL + q * 8];
    const _Float16* Bbase = &Bs[(wc * 64 + m) * SL + q * 8];

    for (int kc = 0; kc < D; kc += KC) {
        __syncthreads();
#pragma unroll
        for (int it = 0; it < 2; ++it) {
            int f = tid + it * 256;
            int row = f >> 2, g = f & 3;
            size_t go = (size_t)kc + g * 8;
            half8 v = *(const half8*)(xh + (size_t)sPi[row] * D + go);
            *(half8*)(&As[row * SL + g * 8]) = v;
            half8 u = *(const half8*)(xh + (size_t)sPj[row] * D + go);
            *(half8*)(&Bs[row * SL + g * 8]) = u;
        }
        __syncthreads();
#pragma unroll
        for (int ks = 0; ks < KC; ks += 16) {
            half8 a0 = *(const half8*)(Abase + ks);
            half8 a1 = *(const half8*)(Abase + 32 * SL + ks);
            half8 b0 = *(const half8*)(Bbase + ks);
            half8 b1 = *(const half8*)(Bbase + 32 * SL + ks);
            acc[0][0] = __builtin_amdgcn_mfma_f32_32x32x16_f16(a0, b0, acc[0][0], 0, 0, 0);
            acc[0][1] = __builtin_amdgcn_mfma_f32_32x32x16_f16(a0, b1, acc[0][1], 0, 0, 0);
            acc[1][0] = __builtin_amdgcn_mfma_f32_32x32x16_f16(a1, b0, acc[1][0], 0, 0, 0);
            acc[1][1] = __builtin_amdgcn_mfma_f32_32x32x16_f16(a1, b1, acc[1][1], 0, 0, 0);
        }
    }

    float sqj[2], e2j[2], e1pj[2]; int labj[2];
#pragma unroll
    for (int tn = 0; tn < 2; ++tn) {
        float4 cj = colE[wc * 64 + tn * 32 + m];
        e2j[tn] = cj.x; e1pj[tn] = cj.y; labj[tn] = __float_as_int(cj.z); sqj[tn] = cj.w;
    }

    // orientation1 (i pos, j neg): u2 = 2*dot + e2i - sq_j ; u1 = e1pi - T[labi][jg]
    // orientation2 (j pos, i neg): u2' = 2*dot + e2j - sq_i; u1' = e1pj - T[labj][ig]
    // each contributes (u + a/2) iff |u| < a/2; only off-diagonal blocks do orientation2
    float local = 0.f;
#pragma unroll
    for (int tm = 0; tm < 2; ++tm) {
        int rbase = wr * 64 + tm * 32 + 4 * q;
#pragma unroll
        for (int rr = 0; rr < 16; ++rr) {
            int row = rbase + (rr & 3) + 8 * (rr >> 2);
            float4 re = rowE[row];
            int labi = __float_as_int(re.z);
            const float* t1p = T + (size_t)labi * N + j0 + wc * 64 + m;
            float ta = t1p[0], tb = t1p[32];
#pragma unroll
            for (int tn = 0; tn < 2; ++tn) {
                int lj = labj[tn];
                if (labi != lj) {
                    float dot = acc[tm][tn][rr];
                    float u2 = fmaf(2.f, dot, re.x - sqj[tn]);
                    if (__builtin_fabsf(u2) < HALFA) local += u2 + HALFA;
                    float u1 = re.y - (tn ? tb : ta);
                    if (__builtin_fabsf(u1) < HALFA) local += u1 + HALFA;
                    if (!diag) {
                        float u2b = fmaf(2.f, dot, e2j[tn] - re.w);
                        if (__builtin_fabsf(u2b) < HALFA) local += u2b + HALFA;
                        float u1b = e1pj[tn] - T[(size_t)lj * N + i0 + row];
                        if (__builtin_fabsf(u1b) < HALFA) local += u1b + HALFA;
                    }
                }
            }
        }
    }

    // block reduce -> one fire-and-forget float atomic
#pragma unroll
    for (int off = 32; off; off >>= 1) local += __shfl_down(local, off);
    __shared__ float wsum[4];
    if (lane == 0) wsum[w] = local;
    __syncthreads();
    if (tid == 0) atomicAdd(out, wsum[0] + wsum[1] + wsum[2] + wsum[3]);
}

// ---------------- launch ----------------

extern "C" void kernel_launch(void* const* d_in, const int* in_sizes, int n_in,
                              void* d_out, int out_size, void* d_ws, size_t ws_size,
                              hipStream_t stream) {
    const float* x = (const float*)d_in[0];
    const int* labels = (const int*)d_in[1];
    float* out = (float*)d_out;

    char* p = (char*)d_ws;
    int* anchor = (int*)p;            p += C * 4;
    float* sq = (float*)p;            p += N * 4;
    float* apP = (float*)p;           p += N * 4;
    int* perm = (int*)p;              p += N * 4;
    p = (char*)(((uintptr_t)p + 255) & ~(uintptr_t)255);
    float* T = (float*)p;             p += (size_t)C * N * 4;   // 16 MB
    _Float16* xh = (_Float16*)p;      // N*D*2 = 2 MB

    hipMemsetAsync(out, 0, sizeof(float), stream);
    k_prep<<<N / 4, 256, 0, stream>>>(x, labels, xh, sq, anchor);
    k_perm<<<1, 1024, 0, stream>>>(labels, perm);
    dim3 gt(C / BT, N / BT);
    k_table<<<gt, 256, 0, stream>>>(xh, labels, anchor, sq, perm, T, apP);
    k_fused<<<NTRI, 256, 0, stream>>>(xh, labels, anchor, sq, apP, perm, T, out);
}

// Round 10
// 131.814 us; speedup vs baseline: 2.8826x; 1.2221x over previous
//
#include <hip/hip_runtime.h>
#include <limits.h>
#include <stdint.h>

#define ALPHA 0.2f
#define HALFA 0.1f
static constexpr int N = 8192;
static constexpr int D = 128;
static constexpr int C = 512;
static constexpr int BT = 128;          // block tile (i and j)
static constexpr int KC = 32;           // k-chunk in fp16 elems (R4-proven)
static constexpr int SL = 40;           // LDS row stride in fp16 (32 + 8 pad, R4-proven)
static constexpr int NB = N / BT;       // 64
static constexpr int NTRI = NB * (NB + 1) / 2;   // 2080 triangle blocks
static constexpr int NT1 = N / 16;      // 512 term1 blocks (16 rows each)
static constexpr int ABIAS = 0x40000000; // anchor: atomicMax(ABIAS - i); 0xAA poison < all

using half8   = __attribute__((ext_vector_type(8))) _Float16;
using half2v  = __attribute__((ext_vector_type(2))) _Float16;
using floatx16 = __attribute__((ext_vector_type(16))) float;

__device__ __forceinline__ floatx16 zerov() { floatx16 v = {0.f}; return v; }

// ---------------- prep: fp16 convert + sq + anchor + zero out ----------------

__global__ void k_prep(const float* __restrict__ x, const int* __restrict__ labels,
                       _Float16* __restrict__ xh, float* __restrict__ sq,
                       int* __restrict__ anchor, float* __restrict__ out) {
    int row = (blockIdx.x * blockDim.x + threadIdx.x) >> 6;
    int lane = threadIdx.x & 63;
    float2 v = ((const float2*)(x + (size_t)row * D))[lane];
    half2v h; h[0] = (_Float16)v.x; h[1] = (_Float16)v.y;
    *(half2v*)(xh + (size_t)row * D + lane * 2) = h;
    float s = v.x * v.x + v.y * v.y;
#pragma unroll
    for (int off = 32; off; off >>= 1) s += __shfl_down(s, off);
    if (lane == 0) {
        sq[row] = s;
        atomicMax(&anchor[labels[row]], ABIAS - row);   // min-index via max-encode
    }
    if (blockIdx.x == 0 && threadIdx.x == 0) out[0] = 0.f;
}

// ---------------- table: T[c][j] = D(anchor_c, x_j); ap[j] = T[lab_j][j] ----------------

__launch_bounds__(256)
__global__ void k_table(const _Float16* __restrict__ xh, const int* __restrict__ labels,
                        const int* __restrict__ anchor, const float* __restrict__ sq,
                        float* __restrict__ T, float* __restrict__ ap) {
    __shared__ __align__(16) _Float16 As[BT * SL];   // anchor rows c0..
    __shared__ __align__(16) _Float16 Bs[BT * SL];   // rows j0..
    __shared__ float sSqA[BT];
    __shared__ float2 colJ[BT];    // (sq_j, lab_j bits)
    __shared__ int sAnc[BT];

    const int c0 = blockIdx.x * BT;
    const int j0 = blockIdx.y * BT;
    const int tid = threadIdx.x;
    const int lane = tid & 63, w = tid >> 6;
    const int wr = w >> 1, wc = w & 1;
    const int m = lane & 31, q = lane >> 5;

    if (tid < BT) {
        int c = c0 + tid;
        int raw = anchor[c];
        int a = (raw > 0) ? (ABIAS - raw) : 0;   // empty label -> dummy row (never read)
        sAnc[tid] = a;
        sSqA[tid] = sq[a];
    } else {
        int t = tid - BT;
        int j = j0 + t;
        colJ[t] = make_float2(sq[j], __int_as_float(labels[j]));
    }

    floatx16 acc[2][2];
    acc[0][0] = zerov(); acc[0][1] = zerov(); acc[1][0] = zerov(); acc[1][1] = zerov();

    const _Float16* Abase = &As[(wr * 64 + m) * SL + q * 8];
    const _Float16* Bbase = &Bs[(wc * 64 + m) * SL + q * 8];

    for (int kc = 0; kc < D; kc += KC) {
        __syncthreads();
#pragma unroll
        for (int it = 0; it < 2; ++it) {
            int f = tid + it * 256;
            int row = f >> 2, g = f & 3;
            size_t go = (size_t)kc + g * 8;
            half8 v = *(const half8*)(xh + (size_t)sAnc[row] * D + go);
            *(half8*)(&As[row * SL + g * 8]) = v;
            half8 u = *(const half8*)(xh + (size_t)(j0 + row) * D + go);
            *(half8*)(&Bs[row * SL + g * 8]) = u;
        }
        __syncthreads();
#pragma unroll
        for (int ks = 0; ks < KC; ks += 16) {
            half8 a0 = *(const half8*)(Abase + ks);
            half8 a1 = *(const half8*)(Abase + 32 * SL + ks);
            half8 b0 = *(const half8*)(Bbase + ks);
            half8 b1 = *(const half8*)(Bbase + 32 * SL + ks);
            acc[0][0] = __builtin_amdgcn_mfma_f32_32x32x16_f16(a0, b0, acc[0][0], 0, 0, 0);
            acc[0][1] = __builtin_amdgcn_mfma_f32_32x32x16_f16(a0, b1, acc[0][1], 0, 0, 0);
            acc[1][0] = __builtin_amdgcn_mfma_f32_32x32x16_f16(a1, b0, acc[1][0], 0, 0, 0);
            acc[1][1] = __builtin_amdgcn_mfma_f32_32x32x16_f16(a1, b1, acc[1][1], 0, 0, 0);
        }
    }

    float sqj[2]; int labj[2];
#pragma unroll
    for (int tn = 0; tn < 2; ++tn) {
        float2 cj = colJ[wc * 64 + tn * 32 + m];
        sqj[tn] = cj.x; labj[tn] = __float_as_int(cj.y);
    }

#pragma unroll
    for (int tm = 0; tm < 2; ++tm) {
        int rbase = wr * 64 + tm * 32 + 4 * q;
#pragma unroll
        for (int rr = 0; rr < 16; ++rr) {
            int row = rbase + (rr & 3) + 8 * (rr >> 2);
            int c = c0 + row;
            float sqa = sSqA[row];
#pragma unroll
            for (int tn = 0; tn < 2; ++tn) {
                int col = wc * 64 + tn * 32 + m;
                float Dv = fmaf(-2.f, acc[tm][tn][rr], sqa + sqj[tn]);
                T[(size_t)c * N + j0 + col] = Dv;
                if (labj[tn] == c) ap[j0 + col] = Dv;
            }
        }
    }
}

// ---------------- mega: term1 stream blocks + term2 triangle blocks ----------------

__launch_bounds__(256)
__global__ void k_mega(const _Float16* __restrict__ xh, const int* __restrict__ labels,
                       const int* __restrict__ anchor, const float* __restrict__ sq,
                       const float* __restrict__ ap, const float* __restrict__ T,
                       float* __restrict__ out) {
    __shared__ __align__(16) _Float16 As[BT * SL];
    __shared__ __align__(16) _Float16 Bs[BT * SL];
    __shared__ float4 rowE[BT];    // (e2i, labi bits, sq_i, -)
    __shared__ float4 colE[BT];    // (e2j, labj bits, sq_j, -)
    __shared__ float wsum[4];

    const int tid = threadIdx.x;
    const int lane = tid & 63, w = tid >> 6;
    float local = 0.f;

    if ((int)blockIdx.x < NT1) {
        // ---- term1: wave-per-row stream over T[lab_m][:] ----
        const int mbase = blockIdx.x * 16;
        const int4* lrow = (const int4*)labels;
#pragma unroll
        for (int it = 0; it < 4; ++it) {
            int mm = mbase + w * 4 + it;
            int lm = labels[mm];
            int a = ABIAS - anchor[lm];
            if (mm == a) continue;               // anchors are not positives
            float e = ap[mm] + HALFA;
            const float4* trow = (const float4*)(T + (size_t)lm * N);
#pragma unroll 4
            for (int ch = 0; ch < 32; ++ch) {
                float4 tv = trow[ch * 64 + lane];
                int4 lv = lrow[ch * 64 + lane];
                float u;
                u = e - tv.x; if (lv.x != lm && __builtin_fabsf(u) < HALFA) local += u + HALFA;
                u = e - tv.y; if (lv.y != lm && __builtin_fabsf(u) < HALFA) local += u + HALFA;
                u = e - tv.z; if (lv.z != lm && __builtin_fabsf(u) < HALFA) local += u + HALFA;
                u = e - tv.w; if (lv.w != lm && __builtin_fabsf(u) < HALFA) local += u + HALFA;
            }
        }
    } else {
        // ---- term2: symmetric Gram triangle, register-only epilogue ----
        int rem = blockIdx.x - NT1, br = 0;
        while (rem >= NB - br) { rem -= NB - br; ++br; }
        const int bc = br + rem;
        const int i0 = br * BT;
        const int j0 = bc * BT;
        const bool diag = (br == bc);
        const int wr = w >> 1, wc = w & 1;
        const int m = lane & 31, q = lane >> 5;

        if (tid < BT) {
            int i = i0 + tid;
            int li = labels[i];
            int a = ABIAS - anchor[li];
            float sqi = sq[i];
            float e2 = (i == a) ? -1e30f : ap[i] + HALFA - sqi;
            rowE[tid] = make_float4(e2, __int_as_float(li), sqi, 0.f);
        } else {
            int t = tid - BT;
            int j = j0 + t;
            int lj = labels[j];
            int a = ABIAS - anchor[lj];
            float sqj = sq[j];
            float e2 = (j == a) ? -1e30f : ap[j] + HALFA - sqj;
            colE[t] = make_float4(e2, __int_as_float(lj), sqj, 0.f);
        }

        floatx16 acc[2][2];
        acc[0][0] = zerov(); acc[0][1] = zerov(); acc[1][0] = zerov(); acc[1][1] = zerov();

        const _Float16* Abase = &As[(wr * 64 + m) * SL + q * 8];
        const _Float16* Bbase = &Bs[(wc * 64 + m) * SL + q * 8];

        for (int kc = 0; kc < D; kc += KC) {
            __syncthreads();
#pragma unroll
            for (int it = 0; it < 2; ++it) {
                int f = tid + it * 256;
                int row = f >> 2, g = f & 3;
                size_t go = (size_t)kc + g * 8;
                half8 v = *(const half8*)(xh + (size_t)(i0 + row) * D + go);
                *(half8*)(&As[row * SL + g * 8]) = v;
                half8 u = *(const half8*)(xh + (size_t)(j0 + row) * D + go);
                *(half8*)(&Bs[row * SL + g * 8]) = u;
            }
            __syncthreads();
#pragma unroll
            for (int ks = 0; ks < KC; ks += 16) {
                half8 a0 = *(const half8*)(Abase + ks);
                half8 a1 = *(const half8*)(Abase + 32 * SL + ks);
                half8 b0 = *(const half8*)(Bbase + ks);
                half8 b1 = *(const half8*)(Bbase + 32 * SL + ks);
                acc[0][0] = __builtin_amdgcn_mfma_f32_32x32x16_f16(a0, b0, acc[0][0], 0, 0, 0);
                acc[0][1] = __builtin_amdgcn_mfma_f32_32x32x16_f16(a0, b1, acc[0][1], 0, 0, 0);
                acc[1][0] = __builtin_amdgcn_mfma_f32_32x32x16_f16(a1, b0, acc[1][0], 0, 0, 0);
                acc[1][1] = __builtin_amdgcn_mfma_f32_32x32x16_f16(a1, b1, acc[1][1], 0, 0, 0);
            }
        }

        float sqj[2], e2j[2]; int labj[2];
#pragma unroll
        for (int tn = 0; tn < 2; ++tn) {
            float4 cj = colE[wc * 64 + tn * 32 + m];
            e2j[tn] = cj.x; labj[tn] = __float_as_int(cj.y); sqj[tn] = cj.z;
        }

        // ori1 (i pos): u2 = 2*dot + e2i - sq_j ; ori2 (j pos): u2b = 2*dot + e2j - sq_i
        // contribute (u + a/2) iff |u| < a/2; ori2 only off-diagonal
#pragma unroll
        for (int tm = 0; tm < 2; ++tm) {
            int rbase = wr * 64 + tm * 32 + 4 * q;
#pragma unroll
            for (int rr = 0; rr < 16; ++rr) {
                int row = rbase + (rr & 3) + 8 * (rr >> 2);
                float4 re = rowE[row];
                float e2i = re.x, sqi = re.z;
                int labi = __float_as_int(re.y);
#pragma unroll
                for (int tn = 0; tn < 2; ++tn) {
                    if (labi != labj[tn]) {
                        float dot = acc[tm][tn][rr];
                        float u2 = fmaf(2.f, dot, e2i - sqj[tn]);
                        if (__builtin_fabsf(u2) < HALFA) local += u2 + HALFA;
                        if (!diag) {
                            float u2b = fmaf(2.f, dot, e2j[tn] - sqi);
                            if (__builtin_fabsf(u2b) < HALFA) local += u2b + HALFA;
                        }
                    }
                }
            }
        }
    }

    // block reduce -> one fire-and-forget float atomic
#pragma unroll
    for (int off = 32; off; off >>= 1) local += __shfl_down(local, off);
    if (lane == 0) wsum[w] = local;
    __syncthreads();
    if (tid == 0) atomicAdd(out, wsum[0] + wsum[1] + wsum[2] + wsum[3]);
}

// ---------------- launch ----------------

extern "C" void kernel_launch(void* const* d_in, const int* in_sizes, int n_in,
                              void* d_out, int out_size, void* d_ws, size_t ws_size,
                              hipStream_t stream) {
    const float* x = (const float*)d_in[0];
    const int* labels = (const int*)d_in[1];
    float* out = (float*)d_out;

    char* p = (char*)d_ws;
    int* anchor = (int*)p;            p += C * 4;
    float* sq = (float*)p;            p += N * 4;
    float* ap = (float*)p;            p += N * 4;
    p = (char*)(((uintptr_t)p + 255) & ~(uintptr_t)255);
    float* T = (float*)p;             p += (size_t)C * N * 4;   // 16 MB
    _Float16* xh = (_Float16*)p;      // N*D*2 = 2 MB

    k_prep<<<N / 4, 256, 0, stream>>>(x, labels, xh, sq, anchor, out);
    dim3 gt(C / BT, N / BT);
    k_table<<<gt, 256, 0, stream>>>(xh, labels, anchor, sq, T, ap);
    k_mega<<<NT1 + NTRI, 256, 0, stream>>>(xh, labels, anchor, sq, ap, T, out);
}

// Round 11
// 123.714 us; speedup vs baseline: 3.0713x; 1.0655x over previous
//
#include <hip/hip_runtime.h>
#include <limits.h>
#include <stdint.h>

#define ALPHA 0.2f
#define HALFA 0.1f
static constexpr int N = 8192;
static constexpr int D = 128;
static constexpr int C = 512;
static constexpr int BT = 128;          // block tile (i and j)
static constexpr int KC = 32;           // k-chunk in fp16 elems (R4-proven)
static constexpr int SL = 40;           // LDS row stride in fp16 (32 + 8 pad, R4-proven)
static constexpr int NB = N / BT;       // 64
static constexpr int NTRI = NB * (NB + 1) / 2;   // 2080 triangle blocks
static constexpr int MAXG = 64;         // max group size staged (Poisson(16); 64 = >8 sigma)
static constexpr int ABIAS = 0x40000000; // anchor: atomicMax(ABIAS - i); 0xAA poison < all

using half8   = __attribute__((ext_vector_type(8))) _Float16;
using half2v  = __attribute__((ext_vector_type(2))) _Float16;
using floatx16 = __attribute__((ext_vector_type(16))) float;

__device__ __forceinline__ floatx16 zerov() { floatx16 v = {0.f}; return v; }

// ---------------- prep: fp16 convert + sq + anchor + group slots + zero out ----------------

__global__ void k_prep(const float* __restrict__ x, const int* __restrict__ labels,
                       _Float16* __restrict__ xh, float* __restrict__ sq,
                       int* __restrict__ anchor, int* __restrict__ cnt,
                       int* __restrict__ members, float* __restrict__ out) {
    int row = (blockIdx.x * blockDim.x + threadIdx.x) >> 6;
    int lane = threadIdx.x & 63;
    float2 v = ((const float2*)(x + (size_t)row * D))[lane];
    half2v h; h[0] = (_Float16)v.x; h[1] = (_Float16)v.y;
    *(half2v*)(xh + (size_t)row * D + lane * 2) = h;
    float s = v.x * v.x + v.y * v.y;
#pragma unroll
    for (int off = 32; off; off >>= 1) s += __shfl_down(s, off);
    if (lane == 0) {
        sq[row] = s;
        int c = labels[row];
        atomicMax(&anchor[c], ABIAS - row);           // min-index via max-encode
        int slot = atomicAdd(&cnt[c], 1);             // cnt zeroed via hipMemsetAsync
        if (slot < MAXG) members[c * MAXG + slot] = row;
    }
    if (blockIdx.x == 0 && threadIdx.x == 0) out[0] = 0.f;
}

// ---------------- table: T[c][j] = D(anchor_c, x_j); ap[j] = T[lab_j][j] ----------------

__launch_bounds__(256)
__global__ void k_table(const _Float16* __restrict__ xh, const int* __restrict__ labels,
                        const int* __restrict__ anchor, const float* __restrict__ sq,
                        float* __restrict__ T, float* __restrict__ ap) {
    __shared__ __align__(16) _Float16 As[BT * SL];   // anchor rows c0..
    __shared__ __align__(16) _Float16 Bs[BT * SL];   // rows j0..
    __shared__ float sSqA[BT];
    __shared__ float2 colJ[BT];    // (sq_j, lab_j bits)
    __shared__ int sAnc[BT];

    const int c0 = blockIdx.x * BT;
    const int j0 = blockIdx.y * BT;
    const int tid = threadIdx.x;
    const int lane = tid & 63, w = tid >> 6;
    const int wr = w >> 1, wc = w & 1;
    const int m = lane & 31, q = lane >> 5;

    if (tid < BT) {
        int c = c0 + tid;
        int raw = anchor[c];
        int a = (raw > 0) ? (ABIAS - raw) : 0;   // empty label -> dummy row (never read)
        sAnc[tid] = a;
        sSqA[tid] = sq[a];
    } else {
        int t = tid - BT;
        int j = j0 + t;
        colJ[t] = make_float2(sq[j], __int_as_float(labels[j]));
    }

    floatx16 acc[2][2];
    acc[0][0] = zerov(); acc[0][1] = zerov(); acc[1][0] = zerov(); acc[1][1] = zerov();

    const _Float16* Abase = &As[(wr * 64 + m) * SL + q * 8];
    const _Float16* Bbase = &Bs[(wc * 64 + m) * SL + q * 8];

    for (int kc = 0; kc < D; kc += KC) {
        __syncthreads();
#pragma unroll
        for (int it = 0; it < 2; ++it) {
            int f = tid + it * 256;
            int row = f >> 2, g = f & 3;
            size_t go = (size_t)kc + g * 8;
            half8 v = *(const half8*)(xh + (size_t)sAnc[row] * D + go);
            *(half8*)(&As[row * SL + g * 8]) = v;
            half8 u = *(const half8*)(xh + (size_t)(j0 + row) * D + go);
            *(half8*)(&Bs[row * SL + g * 8]) = u;
        }
        __syncthreads();
#pragma unroll
        for (int ks = 0; ks < KC; ks += 16) {
            half8 a0 = *(const half8*)(Abase + ks);
            half8 a1 = *(const half8*)(Abase + 32 * SL + ks);
            half8 b0 = *(const half8*)(Bbase + ks);
            half8 b1 = *(const half8*)(Bbase + 32 * SL + ks);
            acc[0][0] = __builtin_amdgcn_mfma_f32_32x32x16_f16(a0, b0, acc[0][0], 0, 0, 0);
            acc[0][1] = __builtin_amdgcn_mfma_f32_32x32x16_f16(a0, b1, acc[0][1], 0, 0, 0);
            acc[1][0] = __builtin_amdgcn_mfma_f32_32x32x16_f16(a1, b0, acc[1][0], 0, 0, 0);
            acc[1][1] = __builtin_amdgcn_mfma_f32_32x32x16_f16(a1, b1, acc[1][1], 0, 0, 0);
        }
    }

    float sqj[2]; int labj[2];
#pragma unroll
    for (int tn = 0; tn < 2; ++tn) {
        float2 cj = colJ[wc * 64 + tn * 32 + m];
        sqj[tn] = cj.x; labj[tn] = __float_as_int(cj.y);
    }

#pragma unroll
    for (int tm = 0; tm < 2; ++tm) {
        int rbase = wr * 64 + tm * 32 + 4 * q;
#pragma unroll
        for (int rr = 0; rr < 16; ++rr) {
            int row = rbase + (rr & 3) + 8 * (rr >> 2);
            int c = c0 + row;
            float sqa = sSqA[row];
#pragma unroll
            for (int tn = 0; tn < 2; ++tn) {
                int col = wc * 64 + tn * 32 + m;
                float Dv = fmaf(-2.f, acc[tm][tn][rr], sqa + sqj[tn]);
                T[(size_t)c * N + j0 + col] = Dv;
                if (labj[tn] == c) ap[j0 + col] = Dv;
            }
        }
    }
}

// ---------------- mega: per-label term1 blocks + term2 triangle blocks ----------------

__launch_bounds__(256)
__global__ void k_mega(const _Float16* __restrict__ xh, const int* __restrict__ labels,
                       const int* __restrict__ anchor, const float* __restrict__ sq,
                       const float* __restrict__ ap, const int* __restrict__ cnt,
                       const int* __restrict__ members, const float* __restrict__ T,
                       float* __restrict__ out) {
    __shared__ __align__(16) _Float16 As[BT * SL];
    __shared__ __align__(16) _Float16 Bs[BT * SL];
    __shared__ float4 rowE[BT];    // (e2i, labi bits, sq_i, -)
    __shared__ float4 colE[BT];    // (e2j, labj bits, sq_j, -)
    __shared__ float wsum[4];

    const int tid = threadIdx.x;
    const int lane = tid & 63, w = tid >> 6;
    float local = 0.f;

    if ((int)blockIdx.x < C) {
        // ---- term1, label c: stream T[c][:] once, hinge against the group e-list ----
        const int c = blockIdx.x;
        __shared__ float sge[MAXG];
        __shared__ int sglen;
        int raw = anchor[c];
        int gc = cnt[c];
        if (raw > 0 && gc >= 2) {
            int a = ABIAS - raw;
            if (tid == 0) sglen = 0;
            __syncthreads();
            if (gc > MAXG) gc = MAXG;
            if (tid < gc) {
                int mm = members[c * MAXG + tid];
                if (mm != a) {
                    int slot = atomicAdd(&sglen, 1);
                    sge[slot] = ap[mm] + HALFA;
                }
            }
            __syncthreads();
            const int glen = sglen;
            const float4* trow = (const float4*)(T + (size_t)c * N);
            const int4* lrow = (const int4*)labels;
#pragma unroll 2
            for (int ch = 0; ch < 8; ++ch) {
                float4 tv = trow[ch * 256 + tid];
                int4 lv = lrow[ch * 256 + tid];
                for (int g = 0; g < glen; ++g) {
                    float e = sge[g];
                    float u;
                    u = e - tv.x; if (lv.x != c && __builtin_fabsf(u) < HALFA) local += u + HALFA;
                    u = e - tv.y; if (lv.y != c && __builtin_fabsf(u) < HALFA) local += u + HALFA;
                    u = e - tv.z; if (lv.z != c && __builtin_fabsf(u) < HALFA) local += u + HALFA;
                    u = e - tv.w; if (lv.w != c && __builtin_fabsf(u) < HALFA) local += u + HALFA;
                }
            }
        }
    } else {
        // ---- term2: symmetric Gram triangle, register-only epilogue ----
        int rem = blockIdx.x - C, br = 0;
        while (rem >= NB - br) { rem -= NB - br; ++br; }
        const int bc = br + rem;
        const int i0 = br * BT;
        const int j0 = bc * BT;
        const bool diag = (br == bc);
        const int wr = w >> 1, wc = w & 1;
        const int m = lane & 31, q = lane >> 5;

        if (tid < BT) {
            int i = i0 + tid;
            int li = labels[i];
            int a = ABIAS - anchor[li];
            float sqi = sq[i];
            float e2 = (i == a) ? -1e30f : ap[i] + HALFA - sqi;
            rowE[tid] = make_float4(e2, __int_as_float(li), sqi, 0.f);
        } else {
            int t = tid - BT;
            int j = j0 + t;
            int lj = labels[j];
            int a = ABIAS - anchor[lj];
            float sqj = sq[j];
            float e2 = (j == a) ? -1e30f : ap[j] + HALFA - sqj;
            colE[t] = make_float4(e2, __int_as_float(lj), sqj, 0.f);
        }

        floatx16 acc[2][2];
        acc[0][0] = zerov(); acc[0][1] = zerov(); acc[1][0] = zerov(); acc[1][1] = zerov();

        const _Float16* Abase = &As[(wr * 64 + m) * SL + q * 8];
        const _Float16* Bbase = &Bs[(wc * 64 + m) * SL + q * 8];

        for (int kc = 0; kc < D; kc += KC) {
            __syncthreads();
#pragma unroll
            for (int it = 0; it < 2; ++it) {
                int f = tid + it * 256;
                int row = f >> 2, g = f & 3;
                size_t go = (size_t)kc + g * 8;
                half8 v = *(const half8*)(xh + (size_t)(i0 + row) * D + go);
                *(half8*)(&As[row * SL + g * 8]) = v;
                half8 u = *(const half8*)(xh + (size_t)(j0 + row) * D + go);
                *(half8*)(&Bs[row * SL + g * 8]) = u;
            }
            __syncthreads();
#pragma unroll
            for (int ks = 0; ks < KC; ks += 16) {
                half8 a0 = *(const half8*)(Abase + ks);
                half8 a1 = *(const half8*)(Abase + 32 * SL + ks);
                half8 b0 = *(const half8*)(Bbase + ks);
                half8 b1 = *(const half8*)(Bbase + 32 * SL + ks);
                acc[0][0] = __builtin_amdgcn_mfma_f32_32x32x16_f16(a0, b0, acc[0][0], 0, 0, 0);
                acc[0][1] = __builtin_amdgcn_mfma_f32_32x32x16_f16(a0, b1, acc[0][1], 0, 0, 0);
                acc[1][0] = __builtin_amdgcn_mfma_f32_32x32x16_f16(a1, b0, acc[1][0], 0, 0, 0);
                acc[1][1] = __builtin_amdgcn_mfma_f32_32x32x16_f16(a1, b1, acc[1][1], 0, 0, 0);
            }
        }

        float sqj[2], e2j[2]; int labj[2];
#pragma unroll
        for (int tn = 0; tn < 2; ++tn) {
            float4 cj = colE[wc * 64 + tn * 32 + m];
            e2j[tn] = cj.x; labj[tn] = __float_as_int(cj.y); sqj[tn] = cj.z;
        }

        // ori1 (i pos): u2 = 2*dot + e2i - sq_j ; ori2 (j pos): u2b = 2*dot + e2j - sq_i
        // contribute (u + a/2) iff |u| < a/2; ori2 only off-diagonal
#pragma unroll
        for (int tm = 0; tm < 2; ++tm) {
            int rbase = wr * 64 + tm * 32 + 4 * q;
#pragma unroll
            for (int rr = 0; rr < 16; ++rr) {
                int row = rbase + (rr & 3) + 8 * (rr >> 2);
                float4 re = rowE[row];
                float e2i = re.x, sqi = re.z;
                int labi = __float_as_int(re.y);
#pragma unroll
                for (int tn = 0; tn < 2; ++tn) {
                    if (labi != labj[tn]) {
                        float dot = acc[tm][tn][rr];
                        float u2 = fmaf(2.f, dot, e2i - sqj[tn]);
                        if (__builtin_fabsf(u2) < HALFA) local += u2 + HALFA;
                        if (!diag) {
                            float u2b = fmaf(2.f, dot, e2j[tn] - sqi);
                            if (__builtin_fabsf(u2b) < HALFA) local += u2b + HALFA;
                        }
                    }
                }
            }
        }
    }

    // block reduce -> one fire-and-forget float atomic
#pragma unroll
    for (int off = 32; off; off >>= 1) local += __shfl_down(local, off);
    if (lane == 0) wsum[w] = local;
    __syncthreads();
    if (tid == 0) atomicAdd(out, wsum[0] + wsum[1] + wsum[2] + wsum[3]);
}

// ---------------- launch ----------------

extern "C" void kernel_launch(void* const* d_in, const int* in_sizes, int n_in,
                              void* d_out, int out_size, void* d_ws, size_t ws_size,
                              hipStream_t stream) {
    const float* x = (const float*)d_in[0];
    const int* labels = (const int*)d_in[1];
    float* out = (float*)d_out;

    char* p = (char*)d_ws;
    int* anchor = (int*)p;            p += C * 4;
    int* cnt = (int*)p;               p += C * 4;
    int* members = (int*)p;           p += C * MAXG * 4;   // 128 KB
    float* sq = (float*)p;            p += N * 4;
    float* ap = (float*)p;            p += N * 4;
    p = (char*)(((uintptr_t)p + 255) & ~(uintptr_t)255);
    float* T = (float*)p;             p += (size_t)C * N * 4;   // 16 MB
    _Float16* xh = (_Float16*)p;      // N*D*2 = 2 MB

    hipMemsetAsync(cnt, 0, C * 4, stream);
    k_prep<<<N / 4, 256, 0, stream>>>(x, labels, xh, sq, anchor, cnt, members, out);
    dim3 gt(C / BT, N / BT);
    k_table<<<gt, 256, 0, stream>>>(xh, labels, anchor, sq, T, ap);
    k_mega<<<C + NTRI, 256, 0, stream>>>(xh, labels, anchor, sq, ap, cnt, members, T, out);
}